// Round 3
// baseline (323.425 us; speedup 1.0000x reference)
//
#include <hip/hip_runtime.h>
#include <hip/hip_bf16.h>

// ModulatedConv2d: B=16, C_in=C_out=128, H=W=128, K=3, S=512.
// I/O dtype: fp32 (per reference). Compute: bf16 MFMA, fp32 accumulate.
// out[b,co,h,w] = sum_{ci,kh,kw} wmod[b,co,ci,kh,kw] * x[b,ci,h+kh-1,w+kw-1]
// wmod = demodulate(weight * s[b,ci]),  s = style @ mod_w^T + mod_b
//
// Round-2 diagnosis: inputs are fp32, not bf16 — reading them as bf16 made
// NaNs from mantissa halves. Workspace: s (fp32 8KB) + wsW (bf16 4.72MB).

#define Bn 16
#define Cc 128
#define HW 128
#define Sv 512

typedef __bf16 bf16x8 __attribute__((ext_vector_type(8)));
typedef float f32x4 __attribute__((ext_vector_type(4)));
typedef float f4 __attribute__((ext_vector_type(4)));
typedef int int4v __attribute__((ext_vector_type(4)));

static __device__ __forceinline__ unsigned short bf16bits(float f) {
    return __builtin_bit_cast(unsigned short, __float2bfloat16(f));
}

// ---------------- kernel 1: s[b][ci] = style[b,:] . mod_w[ci,:] + mod_b[ci]
__global__ __launch_bounds__(128) void k_style(const float* __restrict__ style,
                                               const float* __restrict__ mod_w,
                                               const float* __restrict__ mod_b,
                                               float* __restrict__ s_out) {
    int b = blockIdx.x;
    int ci = threadIdx.x;
    __shared__ float st[Sv];
    for (int k = threadIdx.x; k < Sv; k += 128)
        st[k] = style[b * Sv + k];
    __syncthreads();
    float acc = mod_b[ci];
    const float* mw = mod_w + (size_t)ci * Sv;
    for (int k = 0; k < Sv; k++)
        acc += st[k] * mw[k];
    s_out[b * Cc + ci] = acc;
}

// ---------------- kernel 2: modulate + demodulate (fp32), store bf16 wsW[b][kh*3+kw][co][ci]
__global__ __launch_bounds__(128) void k_mod(const float* __restrict__ weight,
                                             const float* __restrict__ s,
                                             __hip_bfloat16* __restrict__ wsW) {
    int b = blockIdx.x >> 7;
    int co = blockIdx.x & 127;
    int ci = threadIdx.x;
    float sv = s[b * Cc + ci];
    const float* wp = weight + ((size_t)co * Cc + ci) * 9;
    float wv[9];
    float ss = 0.f;
#pragma unroll
    for (int j = 0; j < 9; j++) {
        wv[j] = wp[j] * sv;
        ss += wv[j] * wv[j];
    }
    __shared__ float red[128];
    red[ci] = ss;
    __syncthreads();
    for (int s2 = 64; s2 > 0; s2 >>= 1) {
        if (ci < s2) red[ci] += red[ci + s2];
        __syncthreads();
    }
    float dec = rsqrtf(red[0] + 1e-8f);
#pragma unroll
    for (int j = 0; j < 9; j++) {
        wsW[(((size_t)b * 9 + j) * Cc + co) * Cc + ci] = __float2bfloat16(wv[j] * dec);
    }
}

// ---------------- kernel 3: implicit-GEMM conv via MFMA, fused NCHW->[w][ci] transpose+cvt
// block = (b, h). 4 waves, each computes 64x64 of the 128(co) x 128(w) tile.
// Xs swizzle: element (w,ci) at  w*128 + (((ci>>3) ^ ((w ^ (w>>3))&7))<<3) + (ci&7)
//  - staging b32 writes (ci pairs)                      -> ~4-way conflicts
//  - MFMA B-fragment b128 reads (16 consecutive w rows) -> 2-way = free
__global__ __launch_bounds__(256, 2) void k_conv(const float* __restrict__ x,
                                                 const __hip_bfloat16* __restrict__ wsW,
                                                 float* __restrict__ out) {
    const int LDW = 136;  // Ws pad: row stride 68 dwords == 4 mod 32 -> 2-way reads (free)
    __shared__ __align__(16) __bf16 Xs[128 * 128];  // swizzled [w][ci]
    __shared__ __align__(16) __bf16 Ws[128 * LDW];  // [co][ci]

    int bx = blockIdx.x;
    int b = bx >> 7, h = bx & 127;
    int t = threadIdx.x;
    int lane = t & 63;
    int wvid = t >> 6;
    int wave_m = wvid >> 1, wave_n = wvid & 1;
    int l15 = lane & 15, quad = lane >> 4;

    f32x4 acc[4][4] = {};
    const bf16x8 zfrag = {};

    const float* xb = x + (size_t)b * (Cc * HW * HW);
    const __hip_bfloat16* wbase = wsW + (size_t)b * 9 * (Cc * Cc);

    for (int kh = 0; kh < 3; kh++) {
        int hp = h + kh - 1;
        if ((unsigned)hp >= (unsigned)HW) continue;  // block-uniform

        __syncthreads();  // prior compute reads of Xs done before overwrite
        // stage x[b, :, hp, :] (fp32, w contiguous) -> bf16 swizzled Xs[w][ci]
        const float* xr = xb + (size_t)hp * HW;
#pragma unroll
        for (int it = 0; it < 8; it++) {
            int id = it * 256 + t;   // [0,2048)
            int cp = id >> 5;        // ci-pair [0,64)
            int seg = id & 31;       // w-segment [0,32)
            int ci0 = cp * 2;
            const float* p0 = xr + (size_t)ci0 * (HW * HW) + seg * 4;
            f4 v0 = *(const f4*)p0;
            f4 v1 = *(const f4*)(p0 + HW * HW);
            int cg = cp >> 2;         // ci0 >> 3
            int sub = (cp & 3) * 2;   // ci0 & 7 (even)
#pragma unroll
            for (int j = 0; j < 4; j++) {
                int w = seg * 4 + j;
                int sw = (w ^ (w >> 3)) & 7;
                int off = w * 128 + ((cg ^ sw) << 3) + sub;
                unsigned int pv = (unsigned int)bf16bits(v0[j]) | ((unsigned int)bf16bits(v1[j]) << 16);
                *(unsigned int*)(&Xs[off]) = pv;  // off even -> 4B aligned
            }
        }

        for (int kw = 0; kw < 3; kw++) {
            __syncthreads();  // prior compute reads of Ws done; Xs staging visible
            const __hip_bfloat16* wsrc = wbase + (size_t)(kh * 3 + kw) * (Cc * Cc);
#pragma unroll
            for (int it = 0; it < 8; it++) {
                int id = it * 256 + t;
                int wr = id >> 4, seg = id & 15;
                int4v v = *(const int4v*)(wsrc + id * 8);
                *(int4v*)(&Ws[wr * LDW + seg * 8]) = v;
            }
            __syncthreads();  // Ws staged
            // GEMM: 128(co) x 128(w) x 128(ci) for this (kh,kw)
#pragma unroll
            for (int ks = 0; ks < 4; ks++) {
                int k0 = ks * 32 + quad * 8;
                int kg = k0 >> 3;
                bf16x8 a[4], bfr[4];
#pragma unroll
                for (int mi = 0; mi < 4; mi++) {
                    int co = wave_m * 64 + mi * 16 + l15;
                    a[mi] = *(const bf16x8*)(&Ws[co * LDW + k0]);
                }
#pragma unroll
                for (int ni = 0; ni < 4; ni++) {
                    int w = wave_n * 64 + ni * 16 + l15;
                    int wp = w + kw - 1;
                    bool ok = (unsigned)wp < (unsigned)HW;
                    int wc = ok ? wp : 0;
                    int sw = (wc ^ (wc >> 3)) & 7;
                    bf16x8 bv = *(const bf16x8*)(&Xs[wc * 128 + ((kg ^ sw) << 3)]);
                    bfr[ni] = ok ? bv : zfrag;
                }
#pragma unroll
                for (int mi = 0; mi < 4; mi++)
#pragma unroll
                    for (int ni = 0; ni < 4; ni++)
                        acc[mi][ni] = __builtin_amdgcn_mfma_f32_16x16x32_bf16(a[mi], bfr[ni], acc[mi][ni], 0, 0, 0);
            }
        }
    }

    // epilogue: D row = co = quad*4+r (+16*mi +64*wave_m), col = w = l15 (+16*ni +64*wave_n)
    float* ob = out + (size_t)b * (Cc * HW * HW) + h * HW;
#pragma unroll
    for (int mi = 0; mi < 4; mi++) {
#pragma unroll
        for (int ni = 0; ni < 4; ni++) {
            int w = wave_n * 64 + ni * 16 + l15;
#pragma unroll
            for (int r = 0; r < 4; r++) {
                int co = wave_m * 64 + mi * 16 + quad * 4 + r;
                ob[(size_t)co * (HW * HW) + w] = acc[mi][ni][r];
            }
        }
    }
}

extern "C" void kernel_launch(void* const* d_in, const int* in_sizes, int n_in,
                              void* d_out, int out_size, void* d_ws, size_t ws_size,
                              hipStream_t stream) {
    const float* x      = (const float*)d_in[0];
    const float* style  = (const float*)d_in[1];
    const float* weight = (const float*)d_in[2];
    const float* mod_w  = (const float*)d_in[3];
    const float* mod_b  = (const float*)d_in[4];
    float* out = (float*)d_out;

    // workspace layout: s (fp32, 8KB) | wsW (bf16, 4.72MB)  => 4.5 MiB total
    float* s_ws = (float*)d_ws;
    __hip_bfloat16* wsW = (__hip_bfloat16*)((char*)d_ws + 8192);

    k_style<<<Bn, 128, 0, stream>>>(style, mod_w, mod_b, s_ws);
    k_mod<<<Bn * Cc, 128, 0, stream>>>(weight, s_ws, wsW);
    k_conv<<<Bn * HW, 256, 0, stream>>>(x, wsW, out);
}

// Round 4
// 298.330 us; speedup vs baseline: 1.0841x; 1.0841x over previous
//
#include <hip/hip_runtime.h>
#include <hip/hip_bf16.h>

// ModulatedConv2d: B=16, C_in=C_out=128, H=W=128, K=3, S=512. fp32 I/O.
// Compute: bf16 MFMA (16x16x32), fp32 accumulate.
// out[b,co,h,w] = sum_{ci,kh,kw} wmod[b,co,ci,kh,kw] * x[b,ci,h+kh-1,w+kw-1]
//
// R4: conflict-free Xs transpose staging (audited bank-uniform), Ws staged
// via global_load_lds width=16 from a pre-swizzled global image, edge clamp
// replaced by 130-row zero-padded Xs.

#define Bn 16
#define Cc 128
#define HW 128
#define Sv 512

typedef __bf16 bf16x8 __attribute__((ext_vector_type(8)));
typedef float f32x4 __attribute__((ext_vector_type(4)));
typedef unsigned short ushort8 __attribute__((ext_vector_type(8)));

static __device__ __forceinline__ unsigned short bf16bits(float f) {
    return __builtin_bit_cast(unsigned short, __float2bfloat16(f));
}

static __device__ __forceinline__ void gl_lds16(const void* g, void* l) {
    __builtin_amdgcn_global_load_lds(
        (const __attribute__((address_space(1))) unsigned int*)g,
        (__attribute__((address_space(3))) unsigned int*)l, 16, 0, 0);
}

// ---------------- kernel 1: s[b][ci] = style[b,:] . mod_w[ci,:] + mod_b[ci]
// one wave per (b,ci): coalesced loads, shuffle reduce
__global__ __launch_bounds__(64) void k_style(const float* __restrict__ style,
                                              const float* __restrict__ mod_w,
                                              const float* __restrict__ mod_b,
                                              float* __restrict__ s_out) {
    int b = blockIdx.x >> 7, ci = blockIdx.x & 127;
    int lane = threadIdx.x;
    const float* st = style + (size_t)b * Sv;
    const float* mw = mod_w + (size_t)ci * Sv;
    float acc = 0.f;
#pragma unroll
    for (int k = 0; k < Sv; k += 64)
        acc += st[k + lane] * mw[k + lane];
#pragma unroll
    for (int off = 32; off > 0; off >>= 1)
        acc += __shfl_down(acc, off, 64);
    if (lane == 0) s_out[b * Cc + ci] = acc + mod_b[ci];
}

// ---------------- kernel 2: modulate + demodulate (fp32), store bf16 PRE-SWIZZLED
// wsW[b][j][co][ pos ]  where pos(content ci) = (((ci>>3) ^ (co&7))<<3) + (ci&7)
__global__ __launch_bounds__(128) void k_mod(const float* __restrict__ weight,
                                             const float* __restrict__ s,
                                             __hip_bfloat16* __restrict__ wsW) {
    int b = blockIdx.x >> 7;
    int co = blockIdx.x & 127;
    int ci = threadIdx.x;
    float sv = s[b * Cc + ci];
    const float* wp = weight + ((size_t)co * Cc + ci) * 9;
    float wv[9];
    float ss = 0.f;
#pragma unroll
    for (int j = 0; j < 9; j++) {
        wv[j] = wp[j] * sv;
        ss += wv[j] * wv[j];
    }
    __shared__ float red[128];
    red[ci] = ss;
    __syncthreads();
    for (int s2 = 64; s2 > 0; s2 >>= 1) {
        if (ci < s2) red[ci] += red[ci + s2];
        __syncthreads();
    }
    float dec = rsqrtf(red[0] + 1e-8f);
    int pos = ((((ci >> 3) ^ (co & 7)) << 3) | (ci & 7));
#pragma unroll
    for (int j = 0; j < 9; j++) {
        wsW[(((size_t)b * 9 + j) * Cc + co) * Cc + pos] = __float2bfloat16(wv[j] * dec);
    }
}

// ---------------- kernel 3: implicit-GEMM conv via MFMA
// block = (b, h). 4 waves, each computes 64(co) x 64(w) of the 128x128 tile.
// Xs: 130 rows (row r = x-col r-1; rows 0,129 zero), swizzled:
//     elem (row, ci) at  row*128 + (((ci>>3) ^ (row&7))<<3) + (ci&7)
// Ws: verbatim global_load_lds image of pre-swizzled wsW.
__global__ __launch_bounds__(256, 2) void k_conv(const float* __restrict__ x,
                                                 const __hip_bfloat16* __restrict__ wsW,
                                                 float* __restrict__ out) {
    __shared__ __align__(16) __bf16 Xs[130 * 128];  // 33.3 KB
    __shared__ __align__(16) __bf16 Ws[128 * 128];  // 32 KB

    int bx = blockIdx.x;
    int b = bx >> 7, h = bx & 127;
    int t = threadIdx.x;
    int lane = t & 63;
    int wvid = t >> 6;
    int wave_m = wvid >> 1, wave_n = wvid & 1;
    int l15 = lane & 15, quad = lane >> 4;

    f32x4 acc[4][4] = {};

    const float* xb = x + (size_t)b * (Cc * HW * HW);
    const __hip_bfloat16* wbase = wsW + (size_t)b * 9 * (Cc * Cc);

    // zero edge rows 0 and 129 (once; staging never touches them)
    if (t < 32) {
        int row = (t < 16) ? 0 : 129;
        int g = t & 15;
        *(bf16x8*)(&Xs[row * 128 + g * 8]) = (bf16x8){};
    }

    for (int kh = 0; kh < 3; kh++) {
        int hp = h + kh - 1;
        if ((unsigned)hp >= (unsigned)HW) continue;  // block-uniform; zero contribution

        __syncthreads();  // prior compute reads of Xs done (also orders edge-zeroing)
        // stage x[b, :, hp, :] -> bf16 swizzled Xs rows 1..128
        // item id: w = id&127 (lanes->consecutive w: coalesced), cig = id>>7
        const float* xr = xb + (size_t)hp * HW;
#pragma unroll
        for (int it = 0; it < 8; it++) {
            int id = it * 256 + t;
            int w = id & 127;
            int cig = id >> 7;
            const float* p = xr + (size_t)cig * 8 * (HW * HW) + w;
            ushort8 pk;
#pragma unroll
            for (int j = 0; j < 8; j++)
                pk[j] = bf16bits(p[(size_t)j * (HW * HW)]);
            int row = w + 1;
            int g2 = cig ^ (row & 7);
            *(bf16x8*)(&Xs[row * 128 + (g2 << 3)]) = __builtin_bit_cast(bf16x8, pk);
        }

        for (int kw = 0; kw < 3; kw++) {
            __syncthreads();  // prior reads of Ws done; (kw==0) Xs staging ordered
            // Ws: async copy 32 KB, 8 chunks of 1 KB per wave
            const __hip_bfloat16* wsrc = wbase + (size_t)(kh * 3 + kw) * (Cc * Cc);
#pragma unroll
            for (int it = 0; it < 8; it++) {
                int chunk = wvid * 8 + it;
                gl_lds16(wsrc + chunk * 512 + lane * 8, &Ws[chunk * 512]);
            }
            __syncthreads();  // drains vmcnt -> Ws visible; Xs visible
            // GEMM 128(co) x 128(w) x 128(ci)
#pragma unroll
            for (int ks = 0; ks < 4; ks++) {
                int kg = ks * 4 + quad;  // k0 = kg*8
                bf16x8 a[4], bfr[4];
#pragma unroll
                for (int mi = 0; mi < 4; mi++) {
                    int co = wave_m * 64 + mi * 16 + l15;
                    a[mi] = *(const bf16x8*)(&Ws[co * 128 + ((kg ^ (co & 7)) << 3)]);
                }
#pragma unroll
                for (int ni = 0; ni < 4; ni++) {
                    int row = wave_n * 64 + ni * 16 + l15 + kw;  // x-col w+kw-1 -> row w+kw
                    bfr[ni] = *(const bf16x8*)(&Xs[row * 128 + ((kg ^ (row & 7)) << 3)]);
                }
#pragma unroll
                for (int mi = 0; mi < 4; mi++)
#pragma unroll
                    for (int ni = 0; ni < 4; ni++)
                        acc[mi][ni] = __builtin_amdgcn_mfma_f32_16x16x32_bf16(a[mi], bfr[ni], acc[mi][ni], 0, 0, 0);
            }
        }
    }

    // epilogue: co = quad*4+r (+16*mi +64*wave_m), w = l15 (+16*ni +64*wave_n)
    float* ob = out + (size_t)b * (Cc * HW * HW) + h * HW;
#pragma unroll
    for (int mi = 0; mi < 4; mi++) {
#pragma unroll
        for (int ni = 0; ni < 4; ni++) {
            int w = wave_n * 64 + ni * 16 + l15;
#pragma unroll
            for (int r = 0; r < 4; r++) {
                int co = wave_m * 64 + mi * 16 + quad * 4 + r;
                ob[(size_t)co * (HW * HW) + w] = acc[mi][ni][r];
            }
        }
    }
}

extern "C" void kernel_launch(void* const* d_in, const int* in_sizes, int n_in,
                              void* d_out, int out_size, void* d_ws, size_t ws_size,
                              hipStream_t stream) {
    const float* x      = (const float*)d_in[0];
    const float* style  = (const float*)d_in[1];
    const float* weight = (const float*)d_in[2];
    const float* mod_w  = (const float*)d_in[3];
    const float* mod_b  = (const float*)d_in[4];
    float* out = (float*)d_out;

    // workspace: s (fp32, 8KB) | wsW (bf16, 4.72MB)
    float* s_ws = (float*)d_ws;
    __hip_bfloat16* wsW = (__hip_bfloat16*)((char*)d_ws + 8192);

    k_style<<<Bn * Cc, 64, 0, stream>>>(style, mod_w, mod_b, s_ws);
    k_mod<<<Bn * Cc, 128, 0, stream>>>(weight, s_ws, wsW);
    k_conv<<<Bn * HW, 256, 0, stream>>>(x, wsW, out);
}